// Round 20
// baseline (116.924 us; speedup 1.0000x reference)
//
#include <hip/hip_runtime.h>
#include <stdint.h>

#define DIM     2048
#define NEXP    64
#define NCHUNK  32        // K chunks of 64
#define TPB     64        // tokens per block (pass 1)
#define TAU     5e-5f     // near-tie threshold on relative prob gaps (~9-12 sigma of bf16x3 noise)
#define LCAP    512       // refine list capacity (E~190, +23 sigma)

#define WFRAG_USHORTS (NCHUNK * 8192)        // 512 KB fragment image
#define WT_OFF        (1u << 20)             // byte offset of f32 w-transpose (512 KB)
#define CNT_OFF       (WT_OFF + (1u << 19))  // byte offset of counter
#define LIST_OFF      (CNT_OFF + 16)         // byte offset of token list

typedef __attribute__((ext_vector_type(8))) short bf16x8;
typedef __attribute__((ext_vector_type(8))) unsigned short u16x8;
typedef __attribute__((ext_vector_type(4))) float f32x4;

__device__ inline unsigned short bf16_rne(float f) {
    uint32_t u = __float_as_uint(f);
    return (unsigned short)((u + 0x7FFFu + ((u >> 16) & 1u)) >> 16);
}
__device__ inline float bf16_to_f(unsigned short h) {
    return __uint_as_float(((uint32_t)h) << 16);
}
__device__ inline uint64_t mono64(double d) {
    uint64_t u = (uint64_t)__double_as_longlong(d);
    return (u >> 63) ? ~u : (u | 0x8000000000000000ull);
}
__device__ inline double unmono64(uint64_t m) {
    uint64_t b = (m >> 63) ? (m & 0x7fffffffffffffffull) : ~m;
    return __longlong_as_double((long long)b);
}

#define SPL(F, HV, LV, J)  { unsigned short _h = bf16_rne(F); HV[J] = _h; LV[J] = bf16_rne((F) - bf16_to_f(_h)); }
#define SPLS(F, HV, LV, J) { unsigned short _h = bf16_rne(F); HV[J] = (short)_h; LV[J] = (short)bf16_rne((F) - bf16_to_f(_h)); }

__device__ __forceinline__ void g2l16(const void* g, void* l) {
    __builtin_amdgcn_global_load_lds(
        (__attribute__((address_space(1))) void*)(g),
        (__attribute__((address_space(3))) void*)(l),
        16, 0, 0);
}

// ---- Kernel 0: merged prep — bf16 hi/lo fragment image + f32 transpose + counter zero ----
__global__ __launch_bounds__(256) void wprep_kernel(
    const float* __restrict__ wgt, unsigned short* __restrict__ wf,
    float4* __restrict__ wt, int* __restrict__ cnt)
{
    int g = blockIdx.x * 256 + threadIdx.x;   // 0..32767
    if (g == 0) cnt[0] = 0;
    // f32 transpose: wt[kq*64 + e] = w[e][4kq..4kq+3]
    {
        int e  = g >> 9;
        int kq = g & 511;
        float4 v = *(const float4*)(wgt + (size_t)e * DIM + kq * 4);
        wt[(size_t)kq * 64 + e] = v;
    }
    // bf16 split fragment image (16384 items)
    if (g < 16384) {
        int l = g & 63;
        int t = (g >> 6) & 3;
        int s = (g >> 8) & 1;
        int c = g >> 9;
        int e = (l & 15) + 16 * t;
        int k = c * 64 + s * 32 + ((l >> 4) * 8);
        const float* wp = wgt + (size_t)e * DIM + k;
        float4 f0 = *(const float4*)(wp);
        float4 f1 = *(const float4*)(wp + 4);
        u16x8 h, lo;
        SPL(f0.x, h, lo, 0) SPL(f0.y, h, lo, 1) SPL(f0.z, h, lo, 2) SPL(f0.w, h, lo, 3)
        SPL(f1.x, h, lo, 4) SPL(f1.y, h, lo, 5) SPL(f1.z, h, lo, 6) SPL(f1.w, h, lo, 7)
        size_t base = ((((size_t)(c * 2 + s) * 4 + t) * 2 + 0) * 64 + l) * 8;
        *(u16x8*)(wf + base)       = h;
        *(u16x8*)(wf + base + 512) = lo;   // plane stride = 64*8
    }
}

// stage chunk CC: x tile only (swizzled source -> linear LDS)
#define STAGE_X(CC, XD)                                                           \
    {                                                                             \
        _Pragma("unroll")                                                         \
        for (int s_ = 0; s_ < 4; ++s_) {                                          \
            int idx_ = wave * 256 + s_ * 64 + lane;                               \
            int row_ = idx_ >> 4;                                                 \
            int p_   = idx_ & 15;                                                 \
            int g_   = p_ ^ (row_ & 7);                                           \
            const unsigned char* gsrc_ = (const unsigned char*)x +                \
                (((size_t)(t0 + row_) * DIM + (CC) * 64 + g_ * 4) << 2);          \
            g2l16(gsrc_, (XD) + wave * 4096 + s_ * 1024);                         \
        }                                                                         \
    }

// ---- Pass 1: bf16x3 MFMA GEMM; x via LDS-DMA (double-buffered), B direct from L2 ----
__global__ __launch_bounds__(256) void moe_gate_mfma_kernel(
    const float* __restrict__ x, const unsigned short* __restrict__ wf,
    float* __restrict__ out, int ntok, int* __restrict__ cnt, int* __restrict__ list)
{
    __shared__ __align__(16) unsigned char smem[32768];   // x0|x1, 16 KB each

    const int tid  = threadIdx.x;
    const int wave = tid >> 6;
    const int lane = tid & 63;
    const int t0   = blockIdx.x * TPB;
    const int l15  = lane & 15;
    const int lg   = lane >> 4;

    unsigned char* const xb0 = smem;
    unsigned char* const xb1 = smem + 16384;

    f32x4 acc0 = {0.f,0.f,0.f,0.f}, acc1 = {0.f,0.f,0.f,0.f};
    f32x4 acc2 = {0.f,0.f,0.f,0.f}, acc3 = {0.f,0.f,0.f,0.f};

    STAGE_X(0, xb0);

    const unsigned short* wl = wf + lane * 8;   // per-lane base into fragment image
    const int s7 = l15 & 7;
    for (int c = 0; c < NCHUNK; ++c) {
        __syncthreads();   // x buf[c&1] staged; buf[c&1^1] free
        unsigned char* xcur = (c & 1) ? xb1 : xb0;
        if (c + 1 < NCHUNK) {
            unsigned char* xnxt = (c & 1) ? xb0 : xb1;
            STAGE_X(c + 1, xnxt);
        }

        // ---- A fragments from swizzled x tile ----
        const unsigned char* xrow = xcur + (wave * 16 + l15) * 256;
        float4 fa0 = *(const float4*)(xrow + (((2 * lg)     ^ s7) * 16));
        float4 fa1 = *(const float4*)(xrow + (((2 * lg + 1) ^ s7) * 16));
        float4 fa2 = *(const float4*)(xrow + (((8 + 2 * lg) ^ s7) * 16));
        float4 fa3 = *(const float4*)(xrow + (((9 + 2 * lg) ^ s7) * 16));

        bf16x8 Ah0, Al0, Ah1, Al1;
        SPLS(fa0.x, Ah0, Al0, 0) SPLS(fa0.y, Ah0, Al0, 1) SPLS(fa0.z, Ah0, Al0, 2) SPLS(fa0.w, Ah0, Al0, 3)
        SPLS(fa1.x, Ah0, Al0, 4) SPLS(fa1.y, Ah0, Al0, 5) SPLS(fa1.z, Ah0, Al0, 6) SPLS(fa1.w, Ah0, Al0, 7)
        SPLS(fa2.x, Ah1, Al1, 0) SPLS(fa2.y, Ah1, Al1, 1) SPLS(fa2.z, Ah1, Al1, 2) SPLS(fa2.w, Ah1, Al1, 3)
        SPLS(fa3.x, Ah1, Al1, 4) SPLS(fa3.y, Ah1, Al1, 5) SPLS(fa3.z, Ah1, Al1, 6) SPLS(fa3.w, Ah1, Al1, 7)

        // ---- B fragments DIRECT from L2-resident image; 6 MFMAs per tile ----
        const unsigned short* wc = wl + (size_t)c * 8192;
        {
            bf16x8 Bh0 = *(const bf16x8*)(wc + 0);
            bf16x8 Bl0 = *(const bf16x8*)(wc + 512);
            bf16x8 Bh1 = *(const bf16x8*)(wc + 4096);
            bf16x8 Bl1 = *(const bf16x8*)(wc + 4608);
            acc0 = __builtin_amdgcn_mfma_f32_16x16x32_bf16(Ah0, Bh0, acc0, 0, 0, 0);
            acc0 = __builtin_amdgcn_mfma_f32_16x16x32_bf16(Ah0, Bl0, acc0, 0, 0, 0);
            acc0 = __builtin_amdgcn_mfma_f32_16x16x32_bf16(Al0, Bh0, acc0, 0, 0, 0);
            acc0 = __builtin_amdgcn_mfma_f32_16x16x32_bf16(Ah1, Bh1, acc0, 0, 0, 0);
            acc0 = __builtin_amdgcn_mfma_f32_16x16x32_bf16(Ah1, Bl1, acc0, 0, 0, 0);
            acc0 = __builtin_amdgcn_mfma_f32_16x16x32_bf16(Al1, Bh1, acc0, 0, 0, 0);
        }
        {
            bf16x8 Bh0 = *(const bf16x8*)(wc + 1024);
            bf16x8 Bl0 = *(const bf16x8*)(wc + 1536);
            bf16x8 Bh1 = *(const bf16x8*)(wc + 5120);
            bf16x8 Bl1 = *(const bf16x8*)(wc + 5632);
            acc1 = __builtin_amdgcn_mfma_f32_16x16x32_bf16(Ah0, Bh0, acc1, 0, 0, 0);
            acc1 = __builtin_amdgcn_mfma_f32_16x16x32_bf16(Ah0, Bl0, acc1, 0, 0, 0);
            acc1 = __builtin_amdgcn_mfma_f32_16x16x32_bf16(Al0, Bh0, acc1, 0, 0, 0);
            acc1 = __builtin_amdgcn_mfma_f32_16x16x32_bf16(Ah1, Bh1, acc1, 0, 0, 0);
            acc1 = __builtin_amdgcn_mfma_f32_16x16x32_bf16(Ah1, Bl1, acc1, 0, 0, 0);
            acc1 = __builtin_amdgcn_mfma_f32_16x16x32_bf16(Al1, Bh1, acc1, 0, 0, 0);
        }
        {
            bf16x8 Bh0 = *(const bf16x8*)(wc + 2048);
            bf16x8 Bl0 = *(const bf16x8*)(wc + 2560);
            bf16x8 Bh1 = *(const bf16x8*)(wc + 6144);
            bf16x8 Bl1 = *(const bf16x8*)(wc + 6656);
            acc2 = __builtin_amdgcn_mfma_f32_16x16x32_bf16(Ah0, Bh0, acc2, 0, 0, 0);
            acc2 = __builtin_amdgcn_mfma_f32_16x16x32_bf16(Ah0, Bl0, acc2, 0, 0, 0);
            acc2 = __builtin_amdgcn_mfma_f32_16x16x32_bf16(Al0, Bh0, acc2, 0, 0, 0);
            acc2 = __builtin_amdgcn_mfma_f32_16x16x32_bf16(Ah1, Bh1, acc2, 0, 0, 0);
            acc2 = __builtin_amdgcn_mfma_f32_16x16x32_bf16(Ah1, Bl1, acc2, 0, 0, 0);
            acc2 = __builtin_amdgcn_mfma_f32_16x16x32_bf16(Al1, Bh1, acc2, 0, 0, 0);
        }
        {
            bf16x8 Bh0 = *(const bf16x8*)(wc + 3072);
            bf16x8 Bl0 = *(const bf16x8*)(wc + 3584);
            bf16x8 Bh1 = *(const bf16x8*)(wc + 7168);
            bf16x8 Bl1 = *(const bf16x8*)(wc + 7680);
            acc3 = __builtin_amdgcn_mfma_f32_16x16x32_bf16(Ah0, Bh0, acc3, 0, 0, 0);
            acc3 = __builtin_amdgcn_mfma_f32_16x16x32_bf16(Ah0, Bl0, acc3, 0, 0, 0);
            acc3 = __builtin_amdgcn_mfma_f32_16x16x32_bf16(Al0, Bh0, acc3, 0, 0, 0);
            acc3 = __builtin_amdgcn_mfma_f32_16x16x32_bf16(Ah1, Bh1, acc3, 0, 0, 0);
            acc3 = __builtin_amdgcn_mfma_f32_16x16x32_bf16(Ah1, Bl1, acc3, 0, 0, 0);
            acc3 = __builtin_amdgcn_mfma_f32_16x16x32_bf16(Al1, Bh1, acc3, 0, 0, 0);
        }
    }

    // ---- epilogue: transpose logits via LDS (reuse staging area), per wave ----
    __syncthreads();
    float* lsw = (float*)smem + wave * 1088;   // 16*68 floats per wave (17408 B <= 32768)
    {
        const int rb = lg * 4;
        lsw[(rb + 0) * 68 +  0 + l15] = acc0[0]; lsw[(rb + 1) * 68 +  0 + l15] = acc0[1];
        lsw[(rb + 2) * 68 +  0 + l15] = acc0[2]; lsw[(rb + 3) * 68 +  0 + l15] = acc0[3];
        lsw[(rb + 0) * 68 + 16 + l15] = acc1[0]; lsw[(rb + 1) * 68 + 16 + l15] = acc1[1];
        lsw[(rb + 2) * 68 + 16 + l15] = acc1[2]; lsw[(rb + 3) * 68 + 16 + l15] = acc1[3];
        lsw[(rb + 0) * 68 + 32 + l15] = acc2[0]; lsw[(rb + 1) * 68 + 32 + l15] = acc2[1];
        lsw[(rb + 2) * 68 + 32 + l15] = acc2[2]; lsw[(rb + 3) * 68 + 32 + l15] = acc2[3];
        lsw[(rb + 0) * 68 + 48 + l15] = acc3[0]; lsw[(rb + 1) * 68 + 48 + l15] = acc3[1];
        lsw[(rb + 2) * 68 + 48 + l15] = acc3[2]; lsw[(rb + 3) * 68 + 48 + l15] = acc3[3];
    }
    __syncthreads();

    // ---- softmax + top-8: 4 lanes per token, 16 experts each (R6-R19 construct) ----
    const int tok = l15;
    const int sub = lg;

    float r[16];
#pragma unroll
    for (int k = 0; k < 4; ++k) {
        float4 v = *(const float4*)(&lsw[tok * 68 + sub * 16 + 4 * k]);
        r[4 * k] = v.x; r[4 * k + 1] = v.y; r[4 * k + 2] = v.z; r[4 * k + 3] = v.w;
    }

    float m = r[0];
#pragma unroll
    for (int i = 1; i < 16; ++i) m = fmaxf(m, r[i]);
    m = fmaxf(m, __shfl_xor(m, 16));
    m = fmaxf(m, __shfl_xor(m, 32));

    float ex[16]; float s = 0.f;
#pragma unroll
    for (int i = 0; i < 16; ++i) { ex[i] = expf(r[i] - m); s += ex[i]; }
    s += __shfl_xor(s, 16);
    s += __shfl_xor(s, 32);

    float pr[16];
#pragma unroll
    for (int i = 0; i < 16; ++i) pr[i] = ex[i] / s;

    uint64_t prev = ~0ull;
    float ovals[8]; float oidx[8];
    float prevp = 0.f; int nearf = 0;
#pragma unroll
    for (int p = 0; p < 8; ++p) {
        uint64_t best = 0;
#pragma unroll
        for (int i = 0; i < 16; ++i) {
            uint64_t key = ((uint64_t)__float_as_uint(pr[i]) << 32)
                         | (uint64_t)(63 - (sub * 16 + i));
            if (key < prev && key > best) best = key;
        }
        {
            uint32_t bh = (uint32_t)(best >> 32), bl = (uint32_t)best;
            uint32_t oh = __shfl_xor(bh, 16), ol = __shfl_xor(bl, 16);
            uint64_t ob = ((uint64_t)oh << 32) | ol;
            if (ob > best) best = ob;
            bh = (uint32_t)(best >> 32); bl = (uint32_t)best;
            oh = __shfl_xor(bh, 32); ol = __shfl_xor(bl, 32);
            ob = ((uint64_t)oh << 32) | ol;
            if (ob > best) best = ob;
        }
        prev = best;
        float pv = __uint_as_float((uint32_t)(best >> 32));
        if (p > 0 && (prevp - pv) < TAU * pv) nearf = 1;
        prevp = pv;
        ovals[p] = pv;
        oidx[p]  = (float)(63 - (int)(best & 63));
    }
    {
        uint64_t best = 0;
#pragma unroll
        for (int i = 0; i < 16; ++i) {
            uint64_t key = ((uint64_t)__float_as_uint(pr[i]) << 32)
                         | (uint64_t)(63 - (sub * 16 + i));
            if (key < prev && key > best) best = key;
        }
        {
            uint32_t bh = (uint32_t)(best >> 32), bl = (uint32_t)best;
            uint32_t oh = __shfl_xor(bh, 16), ol = __shfl_xor(bl, 16);
            uint64_t ob = ((uint64_t)oh << 32) | ol;
            if (ob > best) best = ob;
            bh = (uint32_t)(best >> 32); bl = (uint32_t)best;
            oh = __shfl_xor(bh, 32); ol = __shfl_xor(bl, 32);
            ob = ((uint64_t)oh << 32) | ol;
            if (ob > best) best = ob;
        }
        float pv9 = __uint_as_float((uint32_t)(best >> 32));
        if ((prevp - pv9) < TAU * pv9) nearf = 1;
    }

    if (sub == 0) {
        size_t gtok = (size_t)(t0 + wave * 16 + tok);
        float* vo = out + gtok * 8;
        float* io = out + (size_t)ntok * 8 + gtok * 8;
        *(float4*)(vo)     = make_float4(ovals[0], ovals[1], ovals[2], ovals[3]);
        *(float4*)(vo + 4) = make_float4(ovals[4], ovals[5], ovals[6], ovals[7]);
        *(float4*)(io)     = make_float4(oidx[0], oidx[1], oidx[2], oidx[3]);
        *(float4*)(io + 4) = make_float4(oidx[4], oidx[5], oidx[6], oidx[7]);
        if (nearf) {
            int pos = atomicAdd(cnt, 1);
            if (pos < LCAP) list[pos] = (int)gtok;
        }
    }
}

// ------- Pass 2: f64 refinement, compacted list, 1 token/block, 4 waves split K (R19 verbatim) -------
#define QLD(G) \
    float4 wv##G = wq[(size_t)(kq + (G)) * 64 + lane]; \
    float4 xv##G = xq[kq + (G)];
#define QFM(G, A) \
    A = fma((double)xv##G.x, (double)wv##G.x, A); \
    A = fma((double)xv##G.y, (double)wv##G.y, A); \
    A = fma((double)xv##G.z, (double)wv##G.z, A); \
    A = fma((double)xv##G.w, (double)wv##G.w, A);

__global__ __launch_bounds__(256) void moe_gate_refine_kernel(
    const float* __restrict__ x, const float4* __restrict__ wt,
    float* __restrict__ out, int ntok, const int* __restrict__ cnt,
    const int* __restrict__ list)
{
    int c = cnt[0];
    if (c > LCAP) c = LCAP;
    if ((int)blockIdx.x >= c) return;    // block-uniform early exit (before any barrier)
    const int tok = list[blockIdx.x];

    __shared__ double part[4][64];
    const int wv   = threadIdx.x >> 6;   // wave 0..3 = K-quarter
    const int lane = threadIdx.x & 63;   // expert id

    const float4* xq = (const float4*)(x + (size_t)tok * DIM) + wv * 128;
    const float4* wq = wt + (size_t)wv * 128 * 64;

    double a0 = 0.0, a1 = 0.0, a2 = 0.0, a3 = 0.0;
    double a4 = 0.0, a5 = 0.0, a6 = 0.0, a7 = 0.0;
#pragma unroll 2
    for (int kq = 0; kq < 128; kq += 8) {
        QLD(0) QLD(1) QLD(2) QLD(3) QLD(4) QLD(5) QLD(6) QLD(7)
        QFM(0, a0) QFM(1, a1) QFM(2, a2) QFM(3, a3)
        QFM(4, a4) QFM(5, a5) QFM(6, a6) QFM(7, a7)
    }
    part[wv][lane] = ((a0 + a1) + (a2 + a3)) + ((a4 + a5) + (a6 + a7));
    __syncthreads();

    if (wv == 0) {
        double acc = (part[0][lane] + part[1][lane]) + (part[2][lane] + part[3][lane]);

        uint64_t mykey = (mono64(acc) & ~63ull) | (uint64_t)(63 - lane);

        uint64_t mk = mykey;
        {
            unsigned long long o;
            o = __shfl_xor((unsigned long long)mk, 1);  if ((uint64_t)o > mk) mk = (uint64_t)o;
            o = __shfl_xor((unsigned long long)mk, 2);  if ((uint64_t)o > mk) mk = (uint64_t)o;
            o = __shfl_xor((unsigned long long)mk, 4);  if ((uint64_t)o > mk) mk = (uint64_t)o;
            o = __shfl_xor((unsigned long long)mk, 8);  if ((uint64_t)o > mk) mk = (uint64_t)o;
            o = __shfl_xor((unsigned long long)mk, 16); if ((uint64_t)o > mk) mk = (uint64_t)o;
            o = __shfl_xor((unsigned long long)mk, 32); if ((uint64_t)o > mk) mk = (uint64_t)o;
        }
        double md = unmono64(mk & ~63ull);

        float s = expf((float)(acc - md));
        s += __shfl_xor(s, 1);
        s += __shfl_xor(s, 2);
        s += __shfl_xor(s, 4);
        s += __shfl_xor(s, 8);
        s += __shfl_xor(s, 16);
        s += __shfl_xor(s, 32);

        float* vo = out + (size_t)tok * 8;
        float* io = out + (size_t)ntok * 8 + (size_t)tok * 8;

        uint64_t prev = ~0ull;
        for (int q = 0; q < 8; ++q) {
            uint64_t best = (mykey < prev) ? mykey : 0;
            {
                unsigned long long o;
                o = __shfl_xor((unsigned long long)best, 1);  if ((uint64_t)o > best) best = (uint64_t)o;
                o = __shfl_xor((unsigned long long)best, 2);  if ((uint64_t)o > best) best = (uint64_t)o;
                o = __shfl_xor((unsigned long long)best, 4);  if ((uint64_t)o > best) best = (uint64_t)o;
                o = __shfl_xor((unsigned long long)best, 8);  if ((uint64_t)o > best) best = (uint64_t)o;
                o = __shfl_xor((unsigned long long)best, 16); if ((uint64_t)o > best) best = (uint64_t)o;
                o = __shfl_xor((unsigned long long)best, 32); if ((uint64_t)o > best) best = (uint64_t)o;
            }
            prev = best;
            if (lane == 0) {
                vo[q] = expf((float)(unmono64(best & ~63ull) - md)) / s;
                io[q] = (float)(63 - (int)(best & 63ull));
            }
        }
    }
}

extern "C" void kernel_launch(void* const* d_in, const int* in_sizes, int n_in,
                              void* d_out, int out_size, void* d_ws, size_t ws_size,
                              hipStream_t stream) {
    const float* x   = (const float*)d_in[0];
    const float* wgt = (const float*)d_in[1];
    float* out = (float*)d_out;
    const int ntok = in_sizes[0] / DIM;   // 32768

    unsigned short* wf   = (unsigned short*)d_ws;                     // 512 KB fragment image
    float4*         wt   = (float4*)((unsigned char*)d_ws + WT_OFF);  // 512 KB f32 transpose
    int*            cnt  = (int*)((unsigned char*)d_ws + CNT_OFF);
    int*            list = (int*)((unsigned char*)d_ws + LIST_OFF);

    hipLaunchKernelGGL(wprep_kernel, dim3(128), dim3(256), 0, stream, wgt, wf, wt, cnt);
    hipLaunchKernelGGL(moe_gate_mfma_kernel, dim3(ntok / TPB), dim3(256), 0, stream,
                       x, wf, out, ntok, cnt, list);
    hipLaunchKernelGGL(moe_gate_refine_kernel, dim3(LCAP), dim3(256), 0, stream,
                       x, wt, out, ntok, cnt, list);
}

// Round 21
// 88.882 us; speedup vs baseline: 1.3155x; 1.3155x over previous
//
#include <hip/hip_runtime.h>
#include <stdint.h>

#define DIM     2048
#define NEXP    64
#define NCHUNK  32        // K chunks of 64
#define TPB     64        // tokens per block (pass 1)
#define TAU     5e-5f     // near-tie threshold on relative prob gaps (~9-12 sigma of bf16x3 noise)
#define LCAP    512       // refine list capacity (E~190, +23 sigma)

#define WFRAG_USHORTS (NCHUNK * 8192)        // 512 KB fragment image
#define WT_OFF        (1u << 20)             // byte offset of f32 w-transpose (512 KB)
#define CNT_OFF       (WT_OFF + (1u << 19))  // byte offset of counter
#define LIST_OFF      (CNT_OFF + 16)         // byte offset of token list

typedef __attribute__((ext_vector_type(8))) short bf16x8;
typedef __attribute__((ext_vector_type(8))) unsigned short u16x8;
typedef __attribute__((ext_vector_type(4))) float f32x4;

__device__ inline unsigned short bf16_rne(float f) {
    uint32_t u = __float_as_uint(f);
    return (unsigned short)((u + 0x7FFFu + ((u >> 16) & 1u)) >> 16);
}
__device__ inline float bf16_to_f(unsigned short h) {
    return __uint_as_float(((uint32_t)h) << 16);
}
__device__ inline uint64_t mono64(double d) {
    uint64_t u = (uint64_t)__double_as_longlong(d);
    return (u >> 63) ? ~u : (u | 0x8000000000000000ull);
}
__device__ inline double unmono64(uint64_t m) {
    uint64_t b = (m >> 63) ? (m & 0x7fffffffffffffffull) : ~m;
    return __longlong_as_double((long long)b);
}

#define SPL(F, HV, LV, J)  { unsigned short _h = bf16_rne(F); HV[J] = _h; LV[J] = bf16_rne((F) - bf16_to_f(_h)); }
#define SPLS(F, HV, LV, J) { unsigned short _h = bf16_rne(F); HV[J] = (short)_h; LV[J] = (short)bf16_rne((F) - bf16_to_f(_h)); }

__device__ __forceinline__ void g2l16(const void* g, void* l) {
    __builtin_amdgcn_global_load_lds(
        (__attribute__((address_space(1))) void*)(g),
        (__attribute__((address_space(3))) void*)(l),
        16, 0, 0);
}

// ---- Kernel 0: merged prep — bf16 hi/lo fragment image + f32 transpose + counter zero (R20) ----
__global__ __launch_bounds__(256) void wprep_kernel(
    const float* __restrict__ wgt, unsigned short* __restrict__ wf,
    float4* __restrict__ wt, int* __restrict__ cnt)
{
    int g = blockIdx.x * 256 + threadIdx.x;   // 0..32767
    if (g == 0) cnt[0] = 0;
    // f32 transpose: wt[kq*64 + e] = w[e][4kq..4kq+3]
    {
        int e  = g >> 9;
        int kq = g & 511;
        float4 v = *(const float4*)(wgt + (size_t)e * DIM + kq * 4);
        wt[(size_t)kq * 64 + e] = v;
    }
    // bf16 split fragment image (16384 items)
    if (g < 16384) {
        int l = g & 63;
        int t = (g >> 6) & 3;
        int s = (g >> 8) & 1;
        int c = g >> 9;
        int e = (l & 15) + 16 * t;
        int k = c * 64 + s * 32 + ((l >> 4) * 8);
        const float* wp = wgt + (size_t)e * DIM + k;
        float4 f0 = *(const float4*)(wp);
        float4 f1 = *(const float4*)(wp + 4);
        u16x8 h, lo;
        SPL(f0.x, h, lo, 0) SPL(f0.y, h, lo, 1) SPL(f0.z, h, lo, 2) SPL(f0.w, h, lo, 3)
        SPL(f1.x, h, lo, 4) SPL(f1.y, h, lo, 5) SPL(f1.z, h, lo, 6) SPL(f1.w, h, lo, 7)
        size_t base = ((((size_t)(c * 2 + s) * 4 + t) * 2 + 0) * 64 + l) * 8;
        *(u16x8*)(wf + base)       = h;
        *(u16x8*)(wf + base + 512) = lo;   // plane stride = 64*8
    }
}

// stage chunk CC: x tile (swizzled source -> linear LDS) + B tile (linear)  (R12/R19 verbatim)
#define STAGE_CHUNK(CC, XD, BD)                                                   \
    {                                                                             \
        _Pragma("unroll")                                                         \
        for (int s_ = 0; s_ < 4; ++s_) {                                          \
            int idx_ = wave * 256 + s_ * 64 + lane;                               \
            int row_ = idx_ >> 4;                                                 \
            int p_   = idx_ & 15;                                                 \
            int g_   = p_ ^ (row_ & 7);                                           \
            const unsigned char* gsrc_ = (const unsigned char*)x +                \
                (((size_t)(t0 + row_) * DIM + (CC) * 64 + g_ * 4) << 2);          \
            g2l16(gsrc_, (XD) + wave * 4096 + s_ * 1024);                         \
        }                                                                         \
        const unsigned char* wfb_ = (const unsigned char*)wf + (size_t)(CC) * 16384; \
        _Pragma("unroll")                                                         \
        for (int s_ = 0; s_ < 4; ++s_) {                                          \
            g2l16(wfb_ + wave * 4096 + s_ * 1024 + lane * 16,                     \
                  (BD) + wave * 4096 + s_ * 1024);                                \
        }                                                                         \
    }

// ---- Pass 1: bf16x3 MFMA GEMM, BK=64 global_load_lds double-buffered (R19 verbatim) ----
__global__ __launch_bounds__(256) void moe_gate_mfma_kernel(
    const float* __restrict__ x, const unsigned short* __restrict__ wf,
    float* __restrict__ out, int ntok, int* __restrict__ cnt, int* __restrict__ list)
{
    __shared__ __align__(16) unsigned char smem[65536];   // x0|x1|b0|b1, 16 KB each

    const int tid  = threadIdx.x;
    const int wave = tid >> 6;
    const int lane = tid & 63;
    const int t0   = blockIdx.x * TPB;
    const int l15  = lane & 15;
    const int lg   = lane >> 4;

    unsigned char* const xb0 = smem;
    unsigned char* const xb1 = smem + 16384;
    unsigned char* const bb0 = smem + 32768;
    unsigned char* const bb1 = smem + 49152;

    f32x4 acc0 = {0.f,0.f,0.f,0.f}, acc1 = {0.f,0.f,0.f,0.f};
    f32x4 acc2 = {0.f,0.f,0.f,0.f}, acc3 = {0.f,0.f,0.f,0.f};

    STAGE_CHUNK(0, xb0, bb0);

    const int s7 = l15 & 7;
    for (int c = 0; c < NCHUNK; ++c) {
        __syncthreads();
        unsigned char* xcur = (c & 1) ? xb1 : xb0;
        unsigned char* bcur = (c & 1) ? bb1 : bb0;
        if (c + 1 < NCHUNK) {
            unsigned char* xnxt = (c & 1) ? xb0 : xb1;
            unsigned char* bnxt = (c & 1) ? bb0 : bb1;
            STAGE_CHUNK(c + 1, xnxt, bnxt);
        }

        const unsigned char* xrow = xcur + (wave * 16 + l15) * 256;
        float4 fa0 = *(const float4*)(xrow + (((2 * lg)     ^ s7) * 16));
        float4 fa1 = *(const float4*)(xrow + (((2 * lg + 1) ^ s7) * 16));
        float4 fa2 = *(const float4*)(xrow + (((8 + 2 * lg) ^ s7) * 16));
        float4 fa3 = *(const float4*)(xrow + (((9 + 2 * lg) ^ s7) * 16));

        bf16x8 Ah0, Al0, Ah1, Al1;
        SPLS(fa0.x, Ah0, Al0, 0) SPLS(fa0.y, Ah0, Al0, 1) SPLS(fa0.z, Ah0, Al0, 2) SPLS(fa0.w, Ah0, Al0, 3)
        SPLS(fa1.x, Ah0, Al0, 4) SPLS(fa1.y, Ah0, Al0, 5) SPLS(fa1.z, Ah0, Al0, 6) SPLS(fa1.w, Ah0, Al0, 7)
        SPLS(fa2.x, Ah1, Al1, 0) SPLS(fa2.y, Ah1, Al1, 1) SPLS(fa2.z, Ah1, Al1, 2) SPLS(fa2.w, Ah1, Al1, 3)
        SPLS(fa3.x, Ah1, Al1, 4) SPLS(fa3.y, Ah1, Al1, 5) SPLS(fa3.z, Ah1, Al1, 6) SPLS(fa3.w, Ah1, Al1, 7)

        const unsigned short* bu = (const unsigned short*)bcur;
        {
            bf16x8 Bh0 = *(const bf16x8*)(bu +        0 + lane * 8);
            bf16x8 Bl0 = *(const bf16x8*)(bu +      512 + lane * 8);
            bf16x8 Bh1 = *(const bf16x8*)(bu + 4096 + 0 + lane * 8);
            bf16x8 Bl1 = *(const bf16x8*)(bu + 4096 + 512 + lane * 8);
            acc0 = __builtin_amdgcn_mfma_f32_16x16x32_bf16(Ah0, Bh0, acc0, 0, 0, 0);
            acc0 = __builtin_amdgcn_mfma_f32_16x16x32_bf16(Ah0, Bl0, acc0, 0, 0, 0);
            acc0 = __builtin_amdgcn_mfma_f32_16x16x32_bf16(Al0, Bh0, acc0, 0, 0, 0);
            acc0 = __builtin_amdgcn_mfma_f32_16x16x32_bf16(Ah1, Bh1, acc0, 0, 0, 0);
            acc0 = __builtin_amdgcn_mfma_f32_16x16x32_bf16(Ah1, Bl1, acc0, 0, 0, 0);
            acc0 = __builtin_amdgcn_mfma_f32_16x16x32_bf16(Al1, Bh1, acc0, 0, 0, 0);
        }
        {
            bf16x8 Bh0 = *(const bf16x8*)(bu + 1024 + lane * 8);
            bf16x8 Bl0 = *(const bf16x8*)(bu + 1536 + lane * 8);
            bf16x8 Bh1 = *(const bf16x8*)(bu + 5120 + lane * 8);
            bf16x8 Bl1 = *(const bf16x8*)(bu + 5632 + lane * 8);
            acc1 = __builtin_amdgcn_mfma_f32_16x16x32_bf16(Ah0, Bh0, acc1, 0, 0, 0);
            acc1 = __builtin_amdgcn_mfma_f32_16x16x32_bf16(Ah0, Bl0, acc1, 0, 0, 0);
            acc1 = __builtin_amdgcn_mfma_f32_16x16x32_bf16(Al0, Bh0, acc1, 0, 0, 0);
            acc1 = __builtin_amdgcn_mfma_f32_16x16x32_bf16(Ah1, Bh1, acc1, 0, 0, 0);
            acc1 = __builtin_amdgcn_mfma_f32_16x16x32_bf16(Ah1, Bl1, acc1, 0, 0, 0);
            acc1 = __builtin_amdgcn_mfma_f32_16x16x32_bf16(Al1, Bh1, acc1, 0, 0, 0);
        }
        {
            bf16x8 Bh0 = *(const bf16x8*)(bu + 2048 + lane * 8);
            bf16x8 Bl0 = *(const bf16x8*)(bu + 2560 + lane * 8);
            bf16x8 Bh1 = *(const bf16x8*)(bu + 6144 + lane * 8);
            bf16x8 Bl1 = *(const bf16x8*)(bu + 6656 + lane * 8);
            acc2 = __builtin_amdgcn_mfma_f32_16x16x32_bf16(Ah0, Bh0, acc2, 0, 0, 0);
            acc2 = __builtin_amdgcn_mfma_f32_16x16x32_bf16(Ah0, Bl0, acc2, 0, 0, 0);
            acc2 = __builtin_amdgcn_mfma_f32_16x16x32_bf16(Al0, Bh0, acc2, 0, 0, 0);
            acc2 = __builtin_amdgcn_mfma_f32_16x16x32_bf16(Ah1, Bh1, acc2, 0, 0, 0);
            acc2 = __builtin_amdgcn_mfma_f32_16x16x32_bf16(Ah1, Bl1, acc2, 0, 0, 0);
            acc2 = __builtin_amdgcn_mfma_f32_16x16x32_bf16(Al1, Bh1, acc2, 0, 0, 0);
        }
        {
            bf16x8 Bh0 = *(const bf16x8*)(bu + 3072 + lane * 8);
            bf16x8 Bl0 = *(const bf16x8*)(bu + 3584 + lane * 8);
            bf16x8 Bh1 = *(const bf16x8*)(bu + 7168 + lane * 8);
            bf16x8 Bl1 = *(const bf16x8*)(bu + 7680 + lane * 8);
            acc3 = __builtin_amdgcn_mfma_f32_16x16x32_bf16(Ah0, Bh0, acc3, 0, 0, 0);
            acc3 = __builtin_amdgcn_mfma_f32_16x16x32_bf16(Ah0, Bl0, acc3, 0, 0, 0);
            acc3 = __builtin_amdgcn_mfma_f32_16x16x32_bf16(Al0, Bh0, acc3, 0, 0, 0);
            acc3 = __builtin_amdgcn_mfma_f32_16x16x32_bf16(Ah1, Bh1, acc3, 0, 0, 0);
            acc3 = __builtin_amdgcn_mfma_f32_16x16x32_bf16(Ah1, Bl1, acc3, 0, 0, 0);
            acc3 = __builtin_amdgcn_mfma_f32_16x16x32_bf16(Al1, Bh1, acc3, 0, 0, 0);
        }
    }

    // ---- epilogue: transpose logits via LDS (reuse staging area), per wave ----
    __syncthreads();
    float* lsw = (float*)smem + wave * 1088;   // 16*68 floats per wave
    {
        const int rb = lg * 4;
        lsw[(rb + 0) * 68 +  0 + l15] = acc0[0]; lsw[(rb + 1) * 68 +  0 + l15] = acc0[1];
        lsw[(rb + 2) * 68 +  0 + l15] = acc0[2]; lsw[(rb + 3) * 68 +  0 + l15] = acc0[3];
        lsw[(rb + 0) * 68 + 16 + l15] = acc1[0]; lsw[(rb + 1) * 68 + 16 + l15] = acc1[1];
        lsw[(rb + 2) * 68 + 16 + l15] = acc1[2]; lsw[(rb + 3) * 68 + 16 + l15] = acc1[3];
        lsw[(rb + 0) * 68 + 32 + l15] = acc2[0]; lsw[(rb + 1) * 68 + 32 + l15] = acc2[1];
        lsw[(rb + 2) * 68 + 32 + l15] = acc2[2]; lsw[(rb + 3) * 68 + 32 + l15] = acc2[3];
        lsw[(rb + 0) * 68 + 48 + l15] = acc3[0]; lsw[(rb + 1) * 68 + 48 + l15] = acc3[1];
        lsw[(rb + 2) * 68 + 48 + l15] = acc3[2]; lsw[(rb + 3) * 68 + 48 + l15] = acc3[3];
    }
    __syncthreads();

    // ---- softmax + top-8: 4 lanes per token, 16 experts each (R6-R19 construct) ----
    const int tok = l15;
    const int sub = lg;

    float r[16];
#pragma unroll
    for (int k = 0; k < 4; ++k) {
        float4 v = *(const float4*)(&lsw[tok * 68 + sub * 16 + 4 * k]);
        r[4 * k] = v.x; r[4 * k + 1] = v.y; r[4 * k + 2] = v.z; r[4 * k + 3] = v.w;
    }

    float m = r[0];
#pragma unroll
    for (int i = 1; i < 16; ++i) m = fmaxf(m, r[i]);
    m = fmaxf(m, __shfl_xor(m, 16));
    m = fmaxf(m, __shfl_xor(m, 32));

    float ex[16]; float s = 0.f;
#pragma unroll
    for (int i = 0; i < 16; ++i) { ex[i] = expf(r[i] - m); s += ex[i]; }
    s += __shfl_xor(s, 16);
    s += __shfl_xor(s, 32);

    float pr[16];
#pragma unroll
    for (int i = 0; i < 16; ++i) pr[i] = ex[i] / s;

    uint64_t prev = ~0ull;
    float ovals[8]; float oidx[8];
    float prevp = 0.f; int nearf = 0;
#pragma unroll
    for (int p = 0; p < 8; ++p) {
        uint64_t best = 0;
#pragma unroll
        for (int i = 0; i < 16; ++i) {
            uint64_t key = ((uint64_t)__float_as_uint(pr[i]) << 32)
                         | (uint64_t)(63 - (sub * 16 + i));
            if (key < prev && key > best) best = key;
        }
        {
            uint32_t bh = (uint32_t)(best >> 32), bl = (uint32_t)best;
            uint32_t oh = __shfl_xor(bh, 16), ol = __shfl_xor(bl, 16);
            uint64_t ob = ((uint64_t)oh << 32) | ol;
            if (ob > best) best = ob;
            bh = (uint32_t)(best >> 32); bl = (uint32_t)best;
            oh = __shfl_xor(bh, 32); ol = __shfl_xor(bl, 32);
            ob = ((uint64_t)oh << 32) | ol;
            if (ob > best) best = ob;
        }
        prev = best;
        float pv = __uint_as_float((uint32_t)(best >> 32));
        if (p > 0 && (prevp - pv) < TAU * pv) nearf = 1;
        prevp = pv;
        ovals[p] = pv;
        oidx[p]  = (float)(63 - (int)(best & 63));
    }
    {
        uint64_t best = 0;
#pragma unroll
        for (int i = 0; i < 16; ++i) {
            uint64_t key = ((uint64_t)__float_as_uint(pr[i]) << 32)
                         | (uint64_t)(63 - (sub * 16 + i));
            if (key < prev && key > best) best = key;
        }
        {
            uint32_t bh = (uint32_t)(best >> 32), bl = (uint32_t)best;
            uint32_t oh = __shfl_xor(bh, 16), ol = __shfl_xor(bl, 16);
            uint64_t ob = ((uint64_t)oh << 32) | ol;
            if (ob > best) best = ob;
            bh = (uint32_t)(best >> 32); bl = (uint32_t)best;
            oh = __shfl_xor(bh, 32); ol = __shfl_xor(bl, 32);
            ob = ((uint64_t)oh << 32) | ol;
            if (ob > best) best = ob;
        }
        float pv9 = __uint_as_float((uint32_t)(best >> 32));
        if ((prevp - pv9) < TAU * pv9) nearf = 1;
    }

    if (sub == 0) {
        size_t gtok = (size_t)(t0 + wave * 16 + tok);
        float* vo = out + gtok * 8;
        float* io = out + (size_t)ntok * 8 + gtok * 8;
        *(float4*)(vo)     = make_float4(ovals[0], ovals[1], ovals[2], ovals[3]);
        *(float4*)(vo + 4) = make_float4(ovals[4], ovals[5], ovals[6], ovals[7]);
        *(float4*)(io)     = make_float4(oidx[0], oidx[1], oidx[2], oidx[3]);
        *(float4*)(io + 4) = make_float4(oidx[4], oidx[5], oidx[6], oidx[7]);
        if (nearf) {
            int pos = atomicAdd(cnt, 1);
            if (pos < LCAP) list[pos] = (int)gtok;
        }
    }
}

// ------- Pass 2: f64 refinement, compacted list, 1 token/block, 4 waves split K (R19 verbatim) -------
#define QLD(G) \
    float4 wv##G = wq[(size_t)(kq + (G)) * 64 + lane]; \
    float4 xv##G = xq[kq + (G)];
#define QFM(G, A) \
    A = fma((double)xv##G.x, (double)wv##G.x, A); \
    A = fma((double)xv##G.y, (double)wv##G.y, A); \
    A = fma((double)xv##G.z, (double)wv##G.z, A); \
    A = fma((double)xv##G.w, (double)wv##G.w, A);

__global__ __launch_bounds__(256) void moe_gate_refine_kernel(
    const float* __restrict__ x, const float4* __restrict__ wt,
    float* __restrict__ out, int ntok, const int* __restrict__ cnt,
    const int* __restrict__ list)
{
    int c = cnt[0];
    if (c > LCAP) c = LCAP;
    if ((int)blockIdx.x >= c) return;    // block-uniform early exit (before any barrier)
    const int tok = list[blockIdx.x];

    __shared__ double part[4][64];
    const int wv   = threadIdx.x >> 6;   // wave 0..3 = K-quarter
    const int lane = threadIdx.x & 63;   // expert id

    const float4* xq = (const float4*)(x + (size_t)tok * DIM) + wv * 128;
    const float4* wq = wt + (size_t)wv * 128 * 64;

    double a0 = 0.0, a1 = 0.0, a2 = 0.0, a3 = 0.0;
    double a4 = 0.0, a5 = 0.0, a6 = 0.0, a7 = 0.0;
#pragma unroll 2
    for (int kq = 0; kq < 128; kq += 8) {
        QLD(0) QLD(1) QLD(2) QLD(3) QLD(4) QLD(5) QLD(6) QLD(7)
        QFM(0, a0) QFM(1, a1) QFM(2, a2) QFM(3, a3)
        QFM(4, a4) QFM(5, a5) QFM(6, a6) QFM(7, a7)
    }
    part[wv][lane] = ((a0 + a1) + (a2 + a3)) + ((a4 + a5) + (a6 + a7));
    __syncthreads();

    if (wv == 0) {
        double acc = (part[0][lane] + part[1][lane]) + (part[2][lane] + part[3][lane]);

        uint64_t mykey = (mono64(acc) & ~63ull) | (uint64_t)(63 - lane);

        uint64_t mk = mykey;
        {
            unsigned long long o;
            o = __shfl_xor((unsigned long long)mk, 1);  if ((uint64_t)o > mk) mk = (uint64_t)o;
            o = __shfl_xor((unsigned long long)mk, 2);  if ((uint64_t)o > mk) mk = (uint64_t)o;
            o = __shfl_xor((unsigned long long)mk, 4);  if ((uint64_t)o > mk) mk = (uint64_t)o;
            o = __shfl_xor((unsigned long long)mk, 8);  if ((uint64_t)o > mk) mk = (uint64_t)o;
            o = __shfl_xor((unsigned long long)mk, 16); if ((uint64_t)o > mk) mk = (uint64_t)o;
            o = __shfl_xor((unsigned long long)mk, 32); if ((uint64_t)o > mk) mk = (uint64_t)o;
        }
        double md = unmono64(mk & ~63ull);

        float s = expf((float)(acc - md));
        s += __shfl_xor(s, 1);
        s += __shfl_xor(s, 2);
        s += __shfl_xor(s, 4);
        s += __shfl_xor(s, 8);
        s += __shfl_xor(s, 16);
        s += __shfl_xor(s, 32);

        float* vo = out + (size_t)tok * 8;
        float* io = out + (size_t)ntok * 8 + (size_t)tok * 8;

        uint64_t prev = ~0ull;
        for (int q = 0; q < 8; ++q) {
            uint64_t best = (mykey < prev) ? mykey : 0;
            {
                unsigned long long o;
                o = __shfl_xor((unsigned long long)best, 1);  if ((uint64_t)o > best) best = (uint64_t)o;
                o = __shfl_xor((unsigned long long)best, 2);  if ((uint64_t)o > best) best = (uint64_t)o;
                o = __shfl_xor((unsigned long long)best, 4);  if ((uint64_t)o > best) best = (uint64_t)o;
                o = __shfl_xor((unsigned long long)best, 8);  if ((uint64_t)o > best) best = (uint64_t)o;
                o = __shfl_xor((unsigned long long)best, 16); if ((uint64_t)o > best) best = (uint64_t)o;
                o = __shfl_xor((unsigned long long)best, 32); if ((uint64_t)o > best) best = (uint64_t)o;
            }
            prev = best;
            if (lane == 0) {
                vo[q] = expf((float)(unmono64(best & ~63ull) - md)) / s;
                io[q] = (float)(63 - (int)(best & 63ull));
            }
        }
    }
}

extern "C" void kernel_launch(void* const* d_in, const int* in_sizes, int n_in,
                              void* d_out, int out_size, void* d_ws, size_t ws_size,
                              hipStream_t stream) {
    const float* x   = (const float*)d_in[0];
    const float* wgt = (const float*)d_in[1];
    float* out = (float*)d_out;
    const int ntok = in_sizes[0] / DIM;   // 32768

    unsigned short* wf   = (unsigned short*)d_ws;                     // 512 KB fragment image
    float4*         wt   = (float4*)((unsigned char*)d_ws + WT_OFF);  // 512 KB f32 transpose
    int*            cnt  = (int*)((unsigned char*)d_ws + CNT_OFF);
    int*            list = (int*)((unsigned char*)d_ws + LIST_OFF);

    hipLaunchKernelGGL(wprep_kernel, dim3(128), dim3(256), 0, stream, wgt, wf, wt, cnt);
    hipLaunchKernelGGL(moe_gate_mfma_kernel, dim3(ntok / TPB), dim3(256), 0, stream,
                       x, wf, out, ntok, cnt, list);
    hipLaunchKernelGGL(moe_gate_refine_kernel, dim3(LCAP), dim3(256), 0, stream,
                       x, wt, out, ntok, cnt, list);
}